// Round 3
// baseline (2682.128 us; speedup 1.0000x reference)
//
#include <hip/hip_runtime.h>
#include <stdint.h>

// ---------------------------------------------------------------------------
// R3: FULLY FUSED single-pass kernel (decoupled lookback across chunks).
//   4096 tickets = 4 batches x 1024 chunks x 64 pixels. A block runs its
//   chunk through L0(LUT) -> 3x(MFMA dense + scan) -> final dense, keeping
//   activations in regs/LDS. Cross-chunk cumsum carries via per-layer
//   agg/incl lookback (agent-scope atomics + threadfence, ticket-ordered).
//   Carry folds into next layer's bias: base = b + INVN*dot(carry, W).
//   Global traffic: ex(3MB) + aggs(~8MB) + out(25MB)  [was ~830MB staged].
// ---------------------------------------------------------------------------

#define BB 4
#define SP 65536
#define SS 196608
#define CCH 1024
#define NTK 4096
#define INVN (1.0f / 196608.0f)

typedef __attribute__((ext_vector_type(8))) _Float16 half8;
typedef __attribute__((ext_vector_type(4))) float    f32x4;

__device__ __forceinline__ float agload(const float* p) {
    return __hip_atomic_load(p, __ATOMIC_RELAXED, __HIP_MEMORY_SCOPE_AGENT);
}
__device__ __forceinline__ void agstore(float* p, float v) {
    __hip_atomic_store(p, v, __ATOMIC_RELAXED, __HIP_MEMORY_SCOPE_AGENT);
}
__device__ __forceinline__ int agloadi(const int* p) {
    return __hip_atomic_load(p, __ATOMIC_RELAXED, __HIP_MEMORY_SCOPE_AGENT);
}
__device__ __forceinline__ void agstorei(int* p, int v) {
    __hip_atomic_store(p, v, __ATOMIC_RELAXED, __HIP_MEMORY_SCOPE_AGENT);
}

// ---------------- prep: W transposes (f32 + f16) + layer-0 LUT --------------
__global__ __launch_bounds__(256)
void prep(const float* __restrict__ W0, const float* __restrict__ b0,
          const float* __restrict__ Wr, const float* __restrict__ Wfin,
          float* __restrict__ Wt32, _Float16* __restrict__ Wt16,
          float* __restrict__ Wf, float* __restrict__ tab)
{
    int i = blockIdx.x * 256 + threadIdx.x;
    int nth = gridDim.x * 256;
    for (int idx = i; idx < 36864; idx += nth) {     // Wt[l][c][f][d] = Wr[l][c][d][f]
        int d = idx & 63, f = (idx >> 6) & 63, lc = idx >> 12;
        float v = Wr[(size_t)(lc * 64 + d) * 64 + f];
        Wt32[idx] = v;
        Wt16[idx] = (_Float16)v;
    }
    for (int idx = i; idx < 1536; idx += nth) {      // Wf[c][k][d]
        int d = idx & 63, k = (idx >> 6) & 7, c = idx >> 9;
        Wf[idx] = Wfin[(size_t)(c * 64 + d) * 8 + k];
    }
    for (int idx = i; idx < 1536; idx += nth) {      // tab[c][v][f] = relu(W0*x+b0)
        int f = idx & 63, v = (idx >> 6) & 7, c = idx >> 9;
        float xv = v * 0.25f - 1.0f;
        tab[idx] = fmaxf(W0[c * 64 + f] * xv + b0[c * 64 + f], 0.f);
    }
}

// ---------------- the fused kernel ------------------------------------------
__global__ __launch_bounds__(256, 3)
void fused(const int* __restrict__ ex,
           const float* __restrict__ br,        // [3][3][64] rest-layer biases
           const float* __restrict__ bfin,      // [3][8]
           const _Float16* __restrict__ Wt16,   // [3l][3c][64f][64d]
           const float* __restrict__ Wt32,      // same, f32
           const float* __restrict__ Wf,        // [3][8][64]
           const float* __restrict__ tab,       // [3][8][64]
           float* __restrict__ out,
           int* flags, int* counter, float* agg, float* incl)
{
    __shared__ __align__(16) float carry_sh[64];
    __shared__ float basearr[192];
    __shared__ float tot[192];
    __shared__ float seg[3 * 16 * 65];
    __shared__ float pcd[24 * 8];
    __shared__ float scd[24];
    __shared__ int   sticket;
    __shared__ __align__(16) float region0[1536];      // stab, later swf
    __shared__ __align__(16) _Float16 bounce[64 * 72]; // also out-staging alias

    int tid = threadIdx.x;
    if (tid == 0) sticket = atomicAdd(counter, 1);
    for (int i = tid; i < 1536; i += 256) region0[i] = tab[i];
    __syncthreads();
    int tk = sticket;
    int b = tk & 3, ci = tk >> 2;
    int w = tid >> 6, ln = tid & 63, lm = ln & 15, lq = ln >> 4;

    float s[3][4][4];     // local inclusive scan values [c][nt][r]
    float off[3][4];      // in-chunk exclusive segment offsets
    float aval = 0.f;     // wave0: own chunk aggregate (per f-lane)

    // ---- layer 0: LUT -> s (C-layout: pixel row = w*16+lq*4+r, col nt*16+lm)
    {
        int prow = ci * 64 + w * 16 + lq * 4;
        float run[3][4];
#pragma unroll
        for (int c = 0; c < 3; ++c)
#pragma unroll
            for (int nt = 0; nt < 4; ++nt) run[c][nt] = 0.f;
#pragma unroll
        for (int r = 0; r < 4; ++r) {
            const int* ep = ex + ((size_t)b * SP + prow + r) * 3;
            int v0 = ep[0], v1 = ep[1], v2 = ep[2];
#pragma unroll
            for (int nt = 0; nt < 4; ++nt) {
                run[0][nt] += region0[v0 * 64 + nt * 16 + lm];
                run[1][nt] += region0[(8 + v1) * 64 + nt * 16 + lm];
                run[2][nt] += region0[(16 + v2) * 64 + nt * 16 + lm];
                s[0][nt][r] = run[0][nt];
                s[1][nt][r] = run[1][nt];
                s[2][nt][r] = run[2][nt];
            }
        }
    }

    // ---- shared per-layer tails --------------------------------------------
    auto segscan_publish = [&](int layer) {
#pragma unroll
        for (int c = 0; c < 3; ++c)
#pragma unroll
            for (int nt = 0; nt < 4; ++nt)
                seg[c * 1040 + (w * 4 + lq) * 65 + nt * 16 + lm] = s[c][nt][3];
        __syncthreads();
        if (tid < 192) {
            int c = tid >> 6, f = tid & 63;
            float run = 0.f;
#pragma unroll
            for (int sg = 0; sg < 16; ++sg) {
                float v = seg[c * 1040 + sg * 65 + f];
                seg[c * 1040 + sg * 65 + f] = run;
                run += v;
            }
            tot[c * 64 + f] = run;
        }
        __syncthreads();
        if (tid < 64) {
            aval = tot[tid] + tot[64 + tid] + tot[128 + tid];
            agstore(&agg[(size_t)(((layer * 4 + b) << 10) | ci) * 64 + tid], aval);
        }
        if (tid == 0) {
            __threadfence();
            agstorei(&flags[((layer * 4 + b) << 10) | ci], 1);
        }
#pragma unroll
        for (int c = 0; c < 3; ++c)
#pragma unroll
            for (int nt = 0; nt < 4; ++nt)
                off[c][nt] = seg[c * 1040 + (w * 4 + lq) * 65 + nt * 16 + lm];
    };

    auto lookback = [&](int layer) {
        int fb = (layer * 4 + b) << 10;
        if (w == 0) {
            float excl = 0.f;
            if (ci > 0) {
                const int*   fl = flags + fb;
                const float* ag = agg  + (size_t)fb * 64;
                const float* ic = incl + (size_t)fb * 64;
                int j = ci;
                bool done = false;
                while (!done) {
                    int idx = j - 1 - ln;
                    int st = (idx >= 0) ? agloadi(fl + idx) : 2;
                    unsigned long long m2 = __ballot(st == 2);
                    unsigned long long m1 = __ballot(st >= 1);
                    if (m2) {
                        int k0 = __builtin_ctzll(m2);
                        unsigned long long need = k0 ? ((1ull << k0) - 1ull) : 0ull;
                        if ((m1 & need) == need) {
                            __threadfence();
                            for (int k = 0; k < k0; ++k)
                                excl += agload(ag + (size_t)(j - 1 - k) * 64 + ln);
                            int ix = j - 1 - k0;
                            if (ix >= 0) excl += agload(ic + (size_t)ix * 64 + ln);
                            done = true;
                        } else __builtin_amdgcn_s_sleep(2);
                    } else if (m1 == ~0ull) {      // window all agg-ready, j > 64
                        __threadfence();
                        for (int k = 0; k < 64; ++k)
                            excl += agload(ag + (size_t)(j - 1 - k) * 64 + ln);
                        j -= 64;
                        if (j == 0) done = true;
                    } else __builtin_amdgcn_s_sleep(2);
                }
            }
            carry_sh[ln] = excl;
            agstore(&incl[(size_t)(fb | ci) * 64 + ln], excl + aval);
        }
        if (tid == 0) {
            __threadfence();
            agstorei(&flags[fb | ci], 2);
        }
        __syncthreads();     // carry_sh visible to block
    };

    auto basefold = [&](int wl) {
        if (tid < 192) {
            int c = tid >> 6, f = tid & 63;
            const float* wp = Wt32 + (size_t)((wl * 3 + c) * 64 + f) * 64;
            float s0 = 0.f, s1 = 0.f, s2 = 0.f, s3 = 0.f;
#pragma unroll
            for (int d4 = 0; d4 < 16; ++d4) {
                float4 cv = *(const float4*)&carry_sh[d4 * 4];
                float4 wv = *(const float4*)(wp + d4 * 4);
                s0 += cv.x * wv.x; s1 += cv.y * wv.y;
                s2 += cv.z * wv.z; s3 += cv.w * wv.w;
            }
            basearr[c * 64 + f] = br[wl * 192 + c * 64 + f]
                                + INVN * ((s0 + s1) + (s2 + s3));
        }
        __syncthreads();
    };

    // bounce channel-c local-cumsum rows into LDS (f16), used by MFMA / final
    auto bounce_ch = [&](int c) {
        __syncthreads();       // previous bounce consumers done
#pragma unroll
        for (int nt = 0; nt < 4; ++nt) {
#pragma unroll
            for (int r = 0; r < 4; ++r) {
                float S0 = off[0][nt] + s[0][nt][r];
                float S1 = off[1][nt] + s[1][nt][r];
                float S2 = off[2][nt] + s[2][nt][r];
                float P1 = off[1][nt] + (r ? s[1][nt][r - 1] : 0.f);
                float P2 = off[2][nt] + (r ? s[2][nt][r - 1] : 0.f);
                float val = (c == 0) ? S0 + P1 + P2
                          : (c == 1) ? S0 + S1 + P2
                                     : S0 + S1 + S2;
                bounce[(w * 16 + lq * 4 + r) * 72 + nt * 16 + lm] = (_Float16)val;
            }
        }
        __syncthreads();
    };

    // ---- 3 mid layers ------------------------------------------------------
    segscan_publish(0);
    for (int l3 = 1; l3 < 4; ++l3) {
        int wl = l3 - 1;
        half8 af0[3], af1[3];
#pragma unroll
        for (int c = 0; c < 3; ++c) {           // A-frags from LDS bounce
            bounce_ch(c);
            const half8* bb = (const half8*)bounce;
            af0[c] = bb[(w * 16 + lm) * 9 + lq];
            af1[c] = bb[(w * 16 + lm) * 9 + 4 + lq];
        }
        f32x4 acc[3][4];
#pragma unroll
        for (int c = 0; c < 3; ++c) {
#pragma unroll
            for (int nt = 0; nt < 4; ++nt) {
                const half8* bp = (const half8*)(Wt16
                    + (size_t)((wl * 3 + c) * 64 + nt * 16 + lm) * 64);
                f32x4 t = {0.f, 0.f, 0.f, 0.f};
                t = __builtin_amdgcn_mfma_f32_16x16x32_f16(af0[c], bp[lq],     t, 0, 0, 0);
                t = __builtin_amdgcn_mfma_f32_16x16x32_f16(af1[c], bp[4 + lq], t, 0, 0, 0);
                acc[c][nt] = t;
            }
        }
        lookback(wl);       // carry for layer wl  (hidden behind MFMA above)
        basefold(wl);
#pragma unroll
        for (int c = 0; c < 3; ++c)             // relu + local scan
#pragma unroll
            for (int nt = 0; nt < 4; ++nt) {
                float base = basearr[c * 64 + nt * 16 + lm];
                float run = 0.f;
#pragma unroll
                for (int r = 0; r < 4; ++r) {
                    float yv = fmaxf(base + INVN * acc[c][nt][r], 0.f);
                    run += yv;
                    s[c][nt][r] = run;
                }
            }
        segscan_publish(l3);
    }

    // ---- final dense to 8 logits ------------------------------------------
    for (int i = tid; i < 1536; i += 256) region0[i] = Wf[i];   // swf
    float skk[3][2];
    int pix = tid & 63, kq = tid >> 6;
#pragma unroll
    for (int c = 0; c < 3; ++c) {
        bounce_ch(c);      // first barrier also publishes swf writes
        const half8* rp = (const half8*)bounce + pix * 9;
        float a0 = 0.f, a1 = 0.f;
#pragma unroll
        for (int j8 = 0; j8 < 8; ++j8) {
            half8 h = rp[j8];
#pragma unroll
            for (int e = 0; e < 8; ++e) {
                float xv = (float)h[e];
                int d = j8 * 8 + e;
                a0 += xv * region0[(c * 8 + kq * 2)     * 64 + d];
                a1 += xv * region0[(c * 8 + kq * 2 + 1) * 64 + d];
            }
        }
        skk[c][0] = a0; skk[c][1] = a1;
    }
    lookback(3);
    if (tid < 192) {       // scd[c*8+k] = dot(carry3, Wf[c][k][:])
        int pair = tid >> 3, dg = tid & 7;
        float sx = 0.f;
#pragma unroll
        for (int dd = 0; dd < 8; ++dd) {
            int d = dg * 8 + dd;
            sx += carry_sh[d] * region0[pair * 64 + d];
        }
        pcd[pair * 8 + dg] = sx;
    }
    __syncthreads();
    if (tid < 24) {
        float t2 = 0.f;
#pragma unroll
        for (int jj = 0; jj < 8; ++jj) t2 += pcd[tid * 8 + jj];
        scd[tid] = t2;
    }
    __syncthreads();
    float* outst = (float*)bounce;              // 6 KB staging (alias ok now)
#pragma unroll
    for (int c = 0; c < 3; ++c)
#pragma unroll
        for (int u = 0; u < 2; ++u) {
            int k = kq * 2 + u;
            outst[pix * 24 + c * 8 + k] =
                bfin[c * 8 + k] + INVN * (scd[c * 8 + k] + skk[c][u]);
        }
    __syncthreads();
    if (tid < 192) {
        float4 v0 = *(float4*)&outst[tid * 8];
        float4 v1 = *(float4*)&outst[tid * 8 + 4];
        float* op = out + ((size_t)b * SS + (size_t)ci * 192 + tid) * 8;
        *(float4*)op       = v0;
        *(float4*)(op + 4) = v1;
    }
}

// ---------------- host -------------------------------------------------------
extern "C" void kernel_launch(void* const* d_in, const int* in_sizes, int n_in,
                              void* d_out, int out_size, void* d_ws, size_t ws_size,
                              hipStream_t stream)
{
    const int*   ex   = (const int*)d_in[0];
    const float* W0   = (const float*)d_in[1];
    const float* b0   = (const float*)d_in[2];
    const float* Wr   = (const float*)d_in[3];
    const float* br   = (const float*)d_in[4];
    const float* Wfin = (const float*)d_in[5];
    const float* bfin = (const float*)d_in[6];
    float* out = (float*)d_out;

    char* ws = (char*)d_ws;
    int*   flags   = (int*)ws;                              // 4*4096 ints
    int*   counter = (int*)(ws + 65536);
    float* agg     = (float*)(ws + 65792);                  // 4 MB
    float* incl    = (float*)(ws + 65792 + 4194304);        // 4 MB
    float* Wt32    = (float*)(ws + 65792 + 2 * 4194304);    // 144 KB
    _Float16* Wt16 = (_Float16*)((char*)Wt32 + 147456);     // 72 KB
    float* Wf      = (float*)((char*)Wt16 + 73728);
    float* tab     = Wf + 1536;

    hipMemsetAsync(ws, 0, 65792, stream);    // flags + ticket counter
    prep<<<64, 256, 0, stream>>>(W0, b0, Wr, Wfin, Wt32, Wt16, Wf, tab);
    fused<<<NTK, 256, 0, stream>>>(ex, br, bfin, Wt16, Wt32, Wf, tab, out,
                                   flags, counter, agg, incl);
}

// Round 4
// 576.993 us; speedup vs baseline: 4.6485x; 4.6485x over previous
//
#include <hip/hip_runtime.h>
#include <stdint.h>

// ---------------------------------------------------------------------------
// R4: staged pipeline (R2 structure) with restructured mid kernel.
//  Y layout: channel-planar f16 [b][c][pix][64]; Y holds CHUNK-LOCAL flattened
//  cumsum; cross-chunk carry folded into next layer's bias via dot(carry,W).
//  mid4: 256 pixels/block (1024 blocks, all resident), 4 sub-chunks/block,
//  3 barriers per sub-chunk, shuffle-based segment scan, single 3-channel
//  LDS bounce for coalesced half8 stores.
// ---------------------------------------------------------------------------

#define BB   4
#define SP   65536
#define SS   196608
#define CC   1024            // 64-pixel chunks per batch (scan granularity)
#define INVN (1.0f / 196608.0f)

typedef __attribute__((ext_vector_type(8))) _Float16 half8;
typedef __attribute__((ext_vector_type(4))) float    f32x4;

// ---------------- prep: W transposes (f32 + f16) + layer-0 LUT --------------
__global__ __launch_bounds__(256)
void prep(const float* __restrict__ W0, const float* __restrict__ b0,
          const float* __restrict__ Wr, const float* __restrict__ Wfin,
          float* __restrict__ Wt32, _Float16* __restrict__ Wt16,
          float* __restrict__ Wf, float* __restrict__ tab)
{
    int i = blockIdx.x * 256 + threadIdx.x;
    int nth = gridDim.x * 256;
    for (int idx = i; idx < 36864; idx += nth) {     // Wt[l][c][f][d] = Wr[l][c][d][f]
        int d = idx & 63, f = (idx >> 6) & 63, lc = idx >> 12;
        float v = Wr[(size_t)(lc * 64 + d) * 64 + f];
        Wt32[idx] = v;
        Wt16[idx] = (_Float16)v;
    }
    for (int idx = i; idx < 1536; idx += nth) {      // Wf[c][k][d]
        int d = idx & 63, k = (idx >> 6) & 7, c = idx >> 9;
        Wf[idx] = Wfin[(size_t)(c * 64 + d) * 8 + k];
    }
    for (int idx = i; idx < 1536; idx += nth) {      // tab[c][v][f] = relu(W0*x+b0)
        int f = idx & 63, v = (idx >> 6) & 7, c = idx >> 9;
        float xv = v * 0.25f - 1.0f;
        tab[idx] = fmaxf(W0[c * 64 + f] * xv + b0[c * 64 + f], 0.f);
    }
}

// ---------------- layer 0: LUT + local scan + planar f16 store --------------
__global__ __launch_bounds__(256)
void l0_kernel(const int* __restrict__ ex, _Float16* __restrict__ Y,
               float* __restrict__ A, const float* __restrict__ tab)
{
    __shared__ float stab[1536];
    __shared__ float seg[3][4][64];
    int tid = threadIdx.x;
    for (int i = tid; i < 1536; i += 256) stab[i] = tab[i];
    __syncthreads();

    int b = blockIdx.x / CC, ci = blockIdx.x % CC;
    int f = tid & 63, g = tid >> 6;
    int pixbase = ci * 64 + g * 16;

    float y[3][16];
#pragma unroll
    for (int p = 0; p < 16; ++p) {
        const int* ep = ex + ((size_t)b * SP + pixbase + p) * 3;
#pragma unroll
        for (int c = 0; c < 3; ++c) y[c][p] = stab[(c * 8 + ep[c]) * 64 + f];
    }
#pragma unroll
    for (int c = 0; c < 3; ++c)
#pragma unroll
        for (int p = 1; p < 16; ++p) y[c][p] += y[c][p - 1];

#pragma unroll
    for (int c = 0; c < 3; ++c) seg[c][g][f] = y[c][15];
    __syncthreads();

    float off[3];
#pragma unroll
    for (int c = 0; c < 3; ++c) {
        float o = 0.f;
        for (int g2 = 0; g2 < g; ++g2) o += seg[c][g2][f];
        off[c] = o;
    }
    if (g == 0) {
        float agg = 0.f;
#pragma unroll
        for (int c = 0; c < 3; ++c)
#pragma unroll
            for (int g2 = 0; g2 < 4; ++g2) agg += seg[c][g2][f];
        A[((size_t)b * CC + ci) * 64 + f] = agg;
    }

#pragma unroll
    for (int p = 0; p < 16; ++p) {
        float S0 = y[0][p] + off[0], S1 = y[1][p] + off[1], S2 = y[2][p] + off[2];
        float P1 = p ? y[1][p - 1] + off[1] : off[1];
        float P2 = p ? y[2][p - 1] + off[2] : off[2];
        float r0 = S0 + P1 + P2, r1 = S0 + S1 + P2, r2 = S0 + S1 + S2;
        size_t pix = (size_t)pixbase + p;
        Y[((size_t)(b * 3 + 0) * SP + pix) * 64 + f] = (_Float16)r0;
        Y[((size_t)(b * 3 + 1) * SP + pix) * 64 + f] = (_Float16)r1;
        Y[((size_t)(b * 3 + 2) * SP + pix) * 64 + f] = (_Float16)r2;
    }
}

// ---------------- chunk-aggregate exclusive scan (per batch) ----------------
__global__ __launch_bounds__(1024)
void scanA(const float* __restrict__ A, float* __restrict__ carry)
{
    __shared__ float seg[16][65];
    int b = blockIdx.x, tid = threadIdx.x;
    int f = tid & 63, g = tid >> 6;           // g in [0,16)
    const float* ap = A + (size_t)b * CC * 64;
    float* cp = carry + (size_t)b * CC * 64;
    int j0 = g * 64;
    float sum = 0.f;
#pragma unroll
    for (int j8 = 0; j8 < 8; ++j8) {          // 8-wide load batches
        float v[8];
#pragma unroll
        for (int k = 0; k < 8; ++k) v[k] = ap[(size_t)(j0 + j8 * 8 + k) * 64 + f];
#pragma unroll
        for (int k = 0; k < 8; ++k) sum += v[k];
    }
    seg[g][f] = sum;
    __syncthreads();
    float run = 0.f;
    for (int g2 = 0; g2 < g; ++g2) run += seg[g2][f];
#pragma unroll
    for (int j8 = 0; j8 < 8; ++j8) {
        float v[8];
#pragma unroll
        for (int k = 0; k < 8; ++k) v[k] = ap[(size_t)(j0 + j8 * 8 + k) * 64 + f];
#pragma unroll
        for (int k = 0; k < 8; ++k) {
            cp[(size_t)(j0 + j8 * 8 + k) * 64 + f] = run;
            run += v[k];
        }
    }
}

// ---------------- mid layer v4: 256 pixels/block, 3 barriers/sub-chunk ------
// Yin/Yout alias (in-place): each sub-chunk's reads complete (MFMA waits)
// before the block-wide barriers that precede its stores; rows are disjoint
// across sub-chunks and blocks.
__global__ __launch_bounds__(256, 4)
void mid4(const _Float16* Yin, _Float16* Yout,
          const float* __restrict__ carry, float* __restrict__ A,
          const _Float16* __restrict__ W16,   // [3c][64f][64d] f16 (this layer)
          const float* __restrict__ W32,      // [3c][64f][64d] f32
          const float* __restrict__ bias)     // [3][64]
{
    __shared__ float basearr4[4][192];                 // [it][c*64+f]
    __shared__ float wtop[3][4][64];                   // [c][w][f]
    __shared__ __align__(16) _Float16 bounce3[3][64 * 72];

    int tid = threadIdx.x;
    int b = blockIdx.x >> 8, cg = blockIdx.x & 255;    // 256-pixel group
    int w = tid >> 6, ln = tid & 63, lm = ln & 15, lq = ln >> 4;
    int ci0 = cg * 4;

    // prologue: fold all 4 sub-chunk carries into biases (W32 row read once)
    if (tid < 192) {
        int c = tid >> 6, f = tid & 63;
        const float* wp = W32 + (size_t)(c * 64 + f) * 64;
        float4 wr[16];
#pragma unroll
        for (int d4 = 0; d4 < 16; ++d4) wr[d4] = *(const float4*)(wp + d4 * 4);
        float bz = bias[c * 64 + f];
#pragma unroll
        for (int it = 0; it < 4; ++it) {
            const float* cr = carry + ((size_t)b * CC + ci0 + it) * 64;
            float s0 = 0.f, s1 = 0.f, s2 = 0.f, s3 = 0.f;
#pragma unroll
            for (int d4 = 0; d4 < 16; ++d4) {
                float4 cv = *(const float4*)(cr + d4 * 4);
                s0 += cv.x * wr[d4].x; s1 += cv.y * wr[d4].y;
                s2 += cv.z * wr[d4].z; s3 += cv.w * wr[d4].w;
            }
            basearr4[it][tid] = bz + INVN * ((s0 + s1) + (s2 + s3));
        }
    }

    for (int it = 0; it < 4; ++it) {
        int ci = ci0 + it;
        int pb = cg * 256 + it * 64;                   // sub-chunk pixel base
        int p0 = pb + w * 16;                          // wave's m-tile base

        // A-frags (global) + MFMA (B-frags from global, L1-hot: 24KB/layer)
        half8 af0[3], af1[3];
#pragma unroll
        for (int c = 0; c < 3; ++c) {
            const half8* ap = (const half8*)(Yin + ((size_t)(b * 3 + c) * SP + p0 + lm) * 64);
            af0[c] = ap[lq];
            af1[c] = ap[4 + lq];
        }
        f32x4 acc[3][4];
#pragma unroll
        for (int c = 0; c < 3; ++c)
#pragma unroll
            for (int nt = 0; nt < 4; ++nt) {
                const half8* bp = (const half8*)(W16 + (size_t)(c * 64 + nt * 16 + lm) * 64);
                f32x4 t = {0.f, 0.f, 0.f, 0.f};
                t = __builtin_amdgcn_mfma_f32_16x16x32_f16(af0[c], bp[lq],     t, 0, 0, 0);
                t = __builtin_amdgcn_mfma_f32_16x16x32_f16(af1[c], bp[4 + lq], t, 0, 0, 0);
                acc[c][nt] = t;
            }

        __syncthreads();   // B1: basearr ready (it0) + prev-it LDS reads done

        // relu + local 4-pixel scan + wave shuffle scan over lq quads
        float s[3][4][4], wexcl[3][4];
#pragma unroll
        for (int c = 0; c < 3; ++c)
#pragma unroll
            for (int nt = 0; nt < 4; ++nt) {
                float base = basearr4[it][c * 64 + nt * 16 + lm];
                float run = 0.f;
#pragma unroll
                for (int r = 0; r < 4; ++r) {
                    float yv = fmaxf(base + INVN * acc[c][nt][r], 0.f);
                    run += yv;
                    s[c][nt][r] = run;
                }
                float v = run;
                float t1 = __shfl_up(v, 16);
                if (lq >= 1) v += t1;
                float t2 = __shfl_up(v, 32);
                if (lq >= 2) v += t2;
                wexcl[c][nt] = v - run;                 // exclusive within wave
                if (lq == 3) wtop[c][w][nt * 16 + lm] = v;  // wave total
            }

        __syncthreads();   // B2: wtop published

        if (tid < 64) {    // chunk aggregate -> A
            float agg = 0.f;
#pragma unroll
            for (int c = 0; c < 3; ++c)
#pragma unroll
                for (int w2 = 0; w2 < 4; ++w2) agg += wtop[c][w2][tid];
            A[((size_t)b * CC + ci) * 64 + tid] = agg;
        }

        // in-chunk offsets + 3-channel combine into bounce
        float off[3][4];
#pragma unroll
        for (int c = 0; c < 3; ++c)
#pragma unroll
            for (int nt = 0; nt < 4; ++nt) {
                float o = wexcl[c][nt];
#pragma unroll
                for (int w2 = 0; w2 < 3; ++w2)
                    if (w2 < w) o += wtop[c][w2][nt * 16 + lm];
                off[c][nt] = o;
            }
#pragma unroll
        for (int nt = 0; nt < 4; ++nt)
#pragma unroll
            for (int r = 0; r < 4; ++r) {
                float S0 = off[0][nt] + s[0][nt][r];
                float S1 = off[1][nt] + s[1][nt][r];
                float S2 = off[2][nt] + s[2][nt][r];
                float P1 = off[1][nt] + (r ? s[1][nt][r - 1] : 0.f);
                float P2 = off[2][nt] + (r ? s[2][nt][r - 1] : 0.f);
                int row = w * 16 + lq * 4 + r;
                bounce3[0][row * 72 + nt * 16 + lm] = (_Float16)(S0 + P1 + P2);
                bounce3[1][row * 72 + nt * 16 + lm] = (_Float16)(S0 + S1 + P2);
                bounce3[2][row * 72 + nt * 16 + lm] = (_Float16)(S0 + S1 + S2);
            }

        __syncthreads();   // B3: bounce ready

        // coalesced half8 stores: 3ch x 64pix x 8 frags = 1536 = 6 x 256
#pragma unroll
        for (int q = 0; q < 6; ++q) {
            int idx = q * 256 + tid;
            int c = idx >> 9, rem = idx & 511;
            int pix = rem >> 3, f8 = rem & 7;
            half8 v = *(const half8*)&bounce3[c][pix * 72 + f8 * 8];
            ((half8*)(Yout + ((size_t)(b * 3 + c) * SP + pb + pix) * 64))[f8] = v;
        }
    }
}

// ---------------- final dense to 8 logits -----------------------------------
__global__ __launch_bounds__(192)
void final_kernel(const _Float16* __restrict__ Yin,
                  const float* __restrict__ carry,
                  const float* __restrict__ Wf,   // [3][8][64]
                  const float* __restrict__ bf,   // [3][8]
                  float* __restrict__ out)
{
    __shared__ __align__(16) float swf[1536];
    __shared__ float scarry[64];
    __shared__ float pcd[24][8];
    __shared__ float scd[24];
    __shared__ float sbf[24];
    int b = blockIdx.x / CC, ci = blockIdx.x % CC;
    int tid = threadIdx.x;

    for (int i = tid; i < 1536; i += 192) swf[i] = Wf[i];
    if (tid < 64) scarry[tid] = carry[((size_t)b * CC + ci) * 64 + tid];
    if (tid < 24) sbf[tid] = bf[tid];
    __syncthreads();

    {   // scd[c*8+k] = dot(carry, Wf[c][k][:])
        int pair = tid >> 3, dg = tid & 7;
        float sx = 0.f;
#pragma unroll
        for (int dd = 0; dd < 8; ++dd) {
            int d = dg * 8 + dd;
            sx += scarry[d] * swf[pair * 64 + d];
        }
        pcd[pair][dg] = sx;
    }
    __syncthreads();
    if (tid < 24) {
        float t = 0.f;
#pragma unroll
        for (int j = 0; j < 8; ++j) t += pcd[tid][j];
        scd[tid] = t;
    }
    __syncthreads();

    int c = tid >> 6, j = tid & 63;   // wave per channel, thread per pixel
    const half8* xp = (const half8*)(Yin + ((size_t)(b * 3 + c) * SP + ci * 64 + j) * 64);
    half8 h[8];
#pragma unroll
    for (int i = 0; i < 8; ++i) h[i] = xp[i];
    float sk[8];
#pragma unroll
    for (int k = 0; k < 8; ++k) sk[k] = 0.f;
#pragma unroll
    for (int d4 = 0; d4 < 16; ++d4) {
        half8 hv = h[d4 >> 1];
        int o = (d4 & 1) * 4;
        float x0 = (float)hv[o], x1 = (float)hv[o + 1];
        float x2 = (float)hv[o + 2], x3 = (float)hv[o + 3];
#pragma unroll
        for (int k = 0; k < 8; ++k) {
            float4 wv = *(const float4*)&swf[(c * 8 + k) * 64 + d4 * 4];
            sk[k] += x0 * wv.x + x1 * wv.y + x2 * wv.z + x3 * wv.w;
        }
    }
    size_t pos = (size_t)b * SS + (size_t)(ci * 64 + j) * 3 + c;
    float* op = out + pos * 8;
    float o0[8];
#pragma unroll
    for (int k = 0; k < 8; ++k)
        o0[k] = sbf[c * 8 + k] + INVN * (scd[c * 8 + k] + sk[k]);
    *(float4*)(op + 0) = make_float4(o0[0], o0[1], o0[2], o0[3]);
    *(float4*)(op + 4) = make_float4(o0[4], o0[5], o0[6], o0[7]);
}

// ---------------- host -------------------------------------------------------
extern "C" void kernel_launch(void* const* d_in, const int* in_sizes, int n_in,
                              void* d_out, int out_size, void* d_ws, size_t ws_size,
                              hipStream_t stream)
{
    const int*   ex   = (const int*)d_in[0];
    const float* W0   = (const float*)d_in[1];
    const float* b0   = (const float*)d_in[2];
    const float* Wr   = (const float*)d_in[3];
    const float* br   = (const float*)d_in[4];
    const float* Wfin = (const float*)d_in[5];
    const float* bfin = (const float*)d_in[6];
    float* out = (float*)d_out;

    char* ws = (char*)d_ws;
    _Float16* Y = (_Float16*)ws;                              // 100.7 MB
    size_t off = (size_t)BB * 3 * SP * 64 * sizeof(_Float16);
    float* A     = (float*)(ws + off);  off += (size_t)BB * CC * 64 * 4;
    float* carry = (float*)(ws + off);  off += (size_t)BB * CC * 64 * 4;
    float* Wt32  = (float*)(ws + off);  off += 36864 * 4;
    float* Wf    = (float*)(ws + off);  off += 1536 * 4;
    float* tab   = (float*)(ws + off);  off += 1536 * 4;
    _Float16* Wt16 = (_Float16*)(ws + off); off += 36864 * 2;

    prep<<<64, 256, 0, stream>>>(W0, b0, Wr, Wfin, Wt32, Wt16, Wf, tab);
    l0_kernel<<<BB * CC, 256, 0, stream>>>(ex, Y, A, tab);
    scanA<<<BB, 1024, 0, stream>>>(A, carry);
    for (int l = 0; l < 3; ++l) {
        mid4<<<BB * 256, 256, 0, stream>>>(Y, Y, carry, A,
                                           Wt16 + (size_t)l * 12288,
                                           Wt32 + (size_t)l * 12288,
                                           br + (size_t)l * 192);
        scanA<<<BB, 1024, 0, stream>>>(A, carry);
    }
    final_kernel<<<BB * CC, 192, 0, stream>>>(Y, carry, Wf, bfin, out);
}